// Round 2
// baseline (391.246 us; speedup 1.0000x reference)
//
#include <hip/hip_runtime.h>
#include <hip/hip_bf16.h>
#include <stdint.h>

#define T_SZ 2048
#define B_SZ 64
#define H_SZ 256
#define I_SZ 256
#define M_SZ (B_SZ * T_SZ)          // 131072
#define TBH  (T_SZ * B_SZ * H_SZ)   // 33554432

typedef float f32x4 __attribute__((ext_vector_type(4)));
typedef short s16x8 __attribute__((ext_vector_type(8)));

// RTNE fp32 -> bf16 pair packed into one u32 (low = a, high = b)
__device__ __forceinline__ unsigned pack_bf16(float a, float b) {
    unsigned ua = __float_as_uint(a);
    unsigned ub = __float_as_uint(b);
    ua += 0x7fffu + ((ua >> 16) & 1u);
    ub += 0x7fffu + ((ub >> 16) & 1u);
    return (ua >> 16) | (ub & 0xffff0000u);
}

// ---------------------------------------------------------------------------
// prep: gb[b,h] = sum_j h0[b,j]*W_fh[h,j] + b_fi[h] + b_fh[h]
//       + convert W_fi (fp32 HxI) -> bf16 into Wb
// grid 64 blocks x 256 threads
// ---------------------------------------------------------------------------
__global__ void prep_kernel(const float* __restrict__ h0,
                            const float* __restrict__ W_fi,
                            const float* __restrict__ b_fi,
                            const float* __restrict__ W_fh,
                            const float* __restrict__ b_fh,
                            unsigned short* __restrict__ Wb,
                            float* __restrict__ gb) {
    __shared__ float h0s[H_SZ];
    const int b = blockIdx.x;
    const int h = threadIdx.x;
    h0s[h] = h0[b * H_SZ + h];
    __syncthreads();
    const float4* w4 = (const float4*)(W_fh + (size_t)h * H_SZ);
    float acc = 0.f;
#pragma unroll 8
    for (int j = 0; j < H_SZ / 4; ++j) {
        float4 w = w4[j];
        acc = fmaf(w.x, h0s[4 * j + 0], acc);
        acc = fmaf(w.y, h0s[4 * j + 1], acc);
        acc = fmaf(w.z, h0s[4 * j + 2], acc);
        acc = fmaf(w.w, h0s[4 * j + 3], acc);
    }
    gb[b * H_SZ + h] = acc + b_fi[h] + b_fh[h];

    // convert 4 W_fi elements per thread: 64*256*4 = 65536 total
    const int e = (b * 256 + h) * 4;
    float4 wv = *(const float4*)(W_fi + e);
    uint2 pk;
    pk.x = pack_bf16(wv.x, wv.y);
    pk.y = pack_bf16(wv.z, wv.w);
    *(uint2*)(Wb + e) = pk;
}

// ---------------------------------------------------------------------------
// main: gx = x @ W_fi^T as bf16 MFMA GEMM (M=131072, N=256, K=256),
// BARRIER-FREE / LDS-FREE, occupancy-first: 32x32 per-wave tile (acc = 16
// regs, total ~90 incl. prefetch buffers -> 5-6 waves/SIMD vs 3 before).
// Block = 4 waves (2M x 2N) = 64x64 tile; grid = 2048 mt x 4 nt = 8192.
// MFMA fragments loaded straight from global (A: fp32->cvt_pk; B: bf16
// L1/L2-hot); 1-ahead register prefetch of both A and B; full unroll.
// XCD swizzle: all 4 nt-blocks of an mt land on one XCD (round-robin model).
// ---------------------------------------------------------------------------
__global__ __launch_bounds__(256, 5) void lstm_main(
    const float* __restrict__ x,
    const unsigned short* __restrict__ Wb,
    const float* __restrict__ gb,
    const float* __restrict__ c0,
    float* __restrict__ out) {
    const int tid  = threadIdx.x;
    const int lane = tid & 63;
    const int wid  = tid >> 6;

    // XCD grouping: xcd = orig & 7 (round-robin dispatch model).
    // Per XCD: 256 mt-groups x 4 nt, nt fastest -> same-mt blocks co-resident.
    const int orig = blockIdx.x;
    const int xcd  = orig & 7;
    const int slot = orig >> 3;
    const int mt = xcd * 256 + (slot >> 2);
    const int nt = slot & 3;
    const int m0 = mt * 64, n0 = nt * 64;
    const int wm = (wid & 1) * 32, wn = (wid >> 1) * 32;
    const int fr = lane & 15;  // fragment row/col within 16
    const int fq = lane >> 4;  // k-chunk quad

    // per-lane fragment base pointers
    const float* abase = x + (size_t)(m0 + wm + fr) * I_SZ + fq * 8;
    const unsigned short* bbase = Wb + (size_t)(n0 + wn + fr) * I_SZ + fq * 8;

    f32x4 acc[2][2];
#pragma unroll
    for (int mi = 0; mi < 2; ++mi)
#pragma unroll
        for (int ni = 0; ni < 2; ++ni)
            acc[mi][ni] = (f32x4){0.f, 0.f, 0.f, 0.f};

    // prefetch kt=0: A raw fp32 (16 regs) + B bf16 (8 regs)
    float4 alo[2], ahi[2];
    s16x8 bf[2];
#pragma unroll
    for (int mi = 0; mi < 2; ++mi) {
        const float4* p = (const float4*)(abase + mi * 16 * I_SZ);
        alo[mi] = p[0];
        ahi[mi] = p[1];
    }
#pragma unroll
    for (int ni = 0; ni < 2; ++ni)
        bf[ni] = *(const s16x8*)(bbase + ni * 16 * I_SZ);

#pragma unroll
    for (int kt = 0; kt < 8; ++kt) {
        // convert prefetched A -> bf16 fragments (v_cvt_pk_bf16_f32)
        s16x8 af[2];
#pragma unroll
        for (int mi = 0; mi < 2; ++mi) {
            union { s16x8 v; __hip_bfloat162 h[4]; } u;
            u.h[0] = __float22bfloat162_rn(make_float2(alo[mi].x, alo[mi].y));
            u.h[1] = __float22bfloat162_rn(make_float2(alo[mi].z, alo[mi].w));
            u.h[2] = __float22bfloat162_rn(make_float2(ahi[mi].x, ahi[mi].y));
            u.h[3] = __float22bfloat162_rn(make_float2(ahi[mi].z, ahi[mi].w));
            af[mi] = u.v;
        }
        s16x8 bcur[2];
        bcur[0] = bf[0];
        bcur[1] = bf[1];

        // prefetch kt+1 (stays in flight across the MFMA cluster)
        if (kt < 7) {
            const int kof = (kt + 1) * 32;
#pragma unroll
            for (int mi = 0; mi < 2; ++mi) {
                const float4* p = (const float4*)(abase + mi * 16 * I_SZ + kof);
                alo[mi] = p[0];
                ahi[mi] = p[1];
            }
#pragma unroll
            for (int ni = 0; ni < 2; ++ni)
                bf[ni] = *(const s16x8*)(bbase + ni * 16 * I_SZ + kof);
        }

#pragma unroll
        for (int mi = 0; mi < 2; ++mi)
#pragma unroll
            for (int ni = 0; ni < 2; ++ni)
                acc[mi][ni] = __builtin_amdgcn_mfma_f32_16x16x32_bf16(
                    af[mi], bcur[ni], acc[mi][ni], 0, 0, 0);
    }

    // Epilogue: C/D layout col = lane&15, row = (lane>>4)*4 + reg
    // Block's 64 M-rows sit inside one batch b (2048 % 64 == 0).
    const int coln = n0 + wn + fr;
    const int bb = (m0 + wm) >> 11;
    float gbv[2], c0v[2];
#pragma unroll
    for (int ni = 0; ni < 2; ++ni) {
        gbv[ni] = gb[bb * H_SZ + coln + ni * 16];
        c0v[ni] = c0[bb * H_SZ + coln + ni * 16];
    }
#pragma unroll
    for (int mi = 0; mi < 2; ++mi) {
#pragma unroll
        for (int r = 0; r < 4; ++r) {
            const int Mg = m0 + wm + mi * 16 + fq * 4 + r;
            const int tt = Mg & (T_SZ - 1);    // % T
            const int obase = tt * (B_SZ * H_SZ) + bb * H_SZ;
            const bool last = (tt == T_SZ - 1);
#pragma unroll
            for (int ni = 0; ni < 2; ++ni) {
                const int h = coln + ni * 16;
                float g = acc[mi][ni][r] + gbv[ni];
                float gc = fminf(15.f, fmaxf(-15.f, g));
                float e = __expf(-gc);
                float s = __builtin_amdgcn_rcpf(1.f + e);        // sigmoid(g)
                float e2 = e * e;
                float m = (1.f - e2) * __builtin_amdgcn_rcpf(1.f + e2);  // tanh(g)
                float cv = s * (c0v[ni] + m);
                float cc = fminf(15.f, fmaxf(-15.f, cv));
                float ec = __expf(-2.f * cc);
                float th = (1.f - ec) * __builtin_amdgcn_rcpf(1.f + ec); // tanh(c)
                float hv = s * th;
                out[obase + h] = hv;
                if (last) {
                    out[TBH + bb * H_SZ + h] = hv;                 // h_last
                    out[TBH + B_SZ * H_SZ + bb * H_SZ + h] = cv;   // c_last
                }
            }
        }
    }
}

extern "C" void kernel_launch(void* const* d_in, const int* in_sizes, int n_in,
                              void* d_out, int out_size, void* d_ws, size_t ws_size,
                              hipStream_t stream) {
    const float* x    = (const float*)d_in[0];
    const float* h0   = (const float*)d_in[1];
    const float* c0   = (const float*)d_in[2];
    const float* W_fi = (const float*)d_in[3];
    const float* b_fi = (const float*)d_in[4];
    const float* W_fh = (const float*)d_in[5];
    const float* b_fh = (const float*)d_in[6];
    float* out = (float*)d_out;

    unsigned short* Wb = (unsigned short*)d_ws;               // 65536 bf16 = 128 KB
    float* gb = (float*)((char*)d_ws + 131072);               // 16384 fp32 = 64 KB

    hipLaunchKernelGGL(prep_kernel, dim3(B_SZ), dim3(H_SZ), 0, stream,
                       h0, W_fi, b_fi, W_fh, b_fh, Wb, gb);
    hipLaunchKernelGGL(lstm_main, dim3(M_SZ / 64 * 4), dim3(256), 0, stream,
                       x, Wb, gb, c0, out);
}

// Round 4
// 283.088 us; speedup vs baseline: 1.3821x; 1.3821x over previous
//
#include <hip/hip_runtime.h>
#include <hip/hip_bf16.h>
#include <stdint.h>

#define T_SZ 2048
#define B_SZ 64
#define H_SZ 256
#define I_SZ 256
#define M_SZ (B_SZ * T_SZ)          // 131072
#define TBH  (T_SZ * B_SZ * H_SZ)   // 33554432

typedef float f32x4 __attribute__((ext_vector_type(4)));
typedef short s16x8 __attribute__((ext_vector_type(8)));

// RTNE fp32 -> bf16 pair packed into one u32 (low = a, high = b)
__device__ __forceinline__ unsigned pack_bf16(float a, float b) {
    unsigned ua = __float_as_uint(a);
    unsigned ub = __float_as_uint(b);
    ua += 0x7fffu + ((ua >> 16) & 1u);
    ub += 0x7fffu + ((ub >> 16) & 1u);
    return (ua >> 16) | (ub & 0xffff0000u);
}

// ---------------------------------------------------------------------------
// prep: gb[b,h] = sum_j h0[b,j]*W_fh[h,j] + b_fi[h] + b_fh[h]
//       + convert W_fi (fp32 HxI) -> bf16 into Wb
// ---------------------------------------------------------------------------
__global__ void prep_kernel(const float* __restrict__ h0,
                            const float* __restrict__ W_fi,
                            const float* __restrict__ b_fi,
                            const float* __restrict__ W_fh,
                            const float* __restrict__ b_fh,
                            unsigned short* __restrict__ Wb,
                            float* __restrict__ gb) {
    __shared__ float h0s[H_SZ];
    const int b = blockIdx.x;
    const int h = threadIdx.x;
    h0s[h] = h0[b * H_SZ + h];
    __syncthreads();
    const float4* w4 = (const float4*)(W_fh + (size_t)h * H_SZ);
    float acc = 0.f;
#pragma unroll 8
    for (int j = 0; j < H_SZ / 4; ++j) {
        float4 w = w4[j];
        acc = fmaf(w.x, h0s[4 * j + 0], acc);
        acc = fmaf(w.y, h0s[4 * j + 1], acc);
        acc = fmaf(w.z, h0s[4 * j + 2], acc);
        acc = fmaf(w.w, h0s[4 * j + 3], acc);
    }
    gb[b * H_SZ + h] = acc + b_fi[h] + b_fh[h];

    const int e = (b * 256 + h) * 4;
    float4 wv = *(const float4*)(W_fi + e);
    uint2 pk;
    pk.x = pack_bf16(wv.x, wv.y);
    pk.y = pack_bf16(wv.z, wv.w);
    *(uint2*)(Wb + e) = pk;
}

// ---------------------------------------------------------------------------
// main: gx = x @ W_fi^T, M=131072, N=256, K=256, fused LSTM epilogue.
// Block: 64M x 256N (full N -> x read exactly once), 512 thr = 8 waves of
// 32x64 (acc = 32 AGPR). LDS staging, padded stride 40 elems (80 B) ->
// conflict-free ds_read_b128. Pipeline per kt (raw barriers, counted waits):
//   issue G(kt+1) -> cvt A(kt) -> [bar1] -> ds_write(kt) -> lgkmcnt(0)
//   -> [bar2] -> ds_read frags -> MFMA.
// G(kt+1) stays in flight across both barriers (no vmcnt(0) drain).
// (Round-3 resubmit: previous bench died to a container/infra failure;
//  barrier counts are uniform across waves, addresses audited in-bounds.)
// ---------------------------------------------------------------------------
__global__ __launch_bounds__(512, 4) void lstm_main(
    const float* __restrict__ x,
    const unsigned short* __restrict__ Wb,
    const float* __restrict__ gb,
    const float* __restrict__ c0,
    float* __restrict__ out) {
    __shared__ __align__(16) unsigned short As[64 * 40];    //  5.0 KB
    __shared__ __align__(16) unsigned short Bs[256 * 40];   // 20.0 KB

    const int tid  = threadIdx.x;
    const int lane = tid & 63;
    const int wid  = tid >> 6;
    const int m0 = blockIdx.x * 64;
    const int wm = (wid & 1) * 32;
    const int wn = (wid >> 1) * 64;
    const int fr = lane & 15;
    const int fq = lane >> 4;

    // staging: A 64x32 fp32 (512 thr x 1 dwordx4), B 256x32 bf16 (512 x 2 dwordx4)
    const int ar  = tid >> 3, ak  = (tid & 7) * 4;
    const int b0r = tid >> 2, b0k = (tid & 3) * 8;
    const int b1r = (tid + 512) >> 2, b1k = ((tid + 512) & 3) * 8;

    const float*          aG  = x  + (size_t)(m0 + ar) * I_SZ + ak;
    const unsigned short* b0G = Wb + b0r * 256 + b0k;
    const unsigned short* b1G = Wb + b1r * 256 + b1k;
    unsigned short* aL  = As + ar * 40 + ak;
    unsigned short* b0L = Bs + b0r * 40 + b0k;
    unsigned short* b1L = Bs + b1r * 40 + b1k;

    const unsigned short* aF = As + (wm + fr) * 40 + fq * 8;
    const unsigned short* bF = Bs + (wn + fr) * 40 + fq * 8;

    f32x4 acc[2][4];
#pragma unroll
    for (int mi = 0; mi < 2; ++mi)
#pragma unroll
        for (int ni = 0; ni < 4; ++ni)
            acc[mi][ni] = (f32x4){0.f, 0.f, 0.f, 0.f};

    float4 aw[2];
    uint4  bw0[2], bw1[2];
    aw[0]  = *(const float4*)aG;
    bw0[0] = *(const uint4*)b0G;
    bw1[0] = *(const uint4*)b1G;

#pragma unroll
    for (int kt = 0; kt < 8; ++kt) {
        // 1. issue next-tile global loads (stay in flight across barriers)
        if (kt < 7) {
            aw[(kt + 1) & 1]  = *(const float4*)(aG + (kt + 1) * 32);
            bw0[(kt + 1) & 1] = *(const uint4*)(b0G + (kt + 1) * 32);
            bw1[(kt + 1) & 1] = *(const uint4*)(b1G + (kt + 1) * 32);
        }
        // 2. convert current A chunk (compiler inserts counted vmcnt here)
        uint2 ap;
        ap.x = pack_bf16(aw[kt & 1].x, aw[kt & 1].y);
        ap.y = pack_bf16(aw[kt & 1].z, aw[kt & 1].w);
        // 3. bar1: all waves finished reading LDS tile kt-1
        if (kt) {
            __builtin_amdgcn_sched_barrier(0);
            __builtin_amdgcn_s_barrier();
            __builtin_amdgcn_sched_barrier(0);
        }
        // 4. stage tile kt into LDS
        *(uint2*)aL  = ap;
        *(uint4*)b0L = bw0[kt & 1];
        *(uint4*)b1L = bw1[kt & 1];
        // 5. bar2: writes visible (LDS only -> lgkmcnt, NOT vmcnt)
        asm volatile("s_waitcnt lgkmcnt(0)" ::: "memory");
        __builtin_amdgcn_sched_barrier(0);
        __builtin_amdgcn_s_barrier();
        __builtin_amdgcn_sched_barrier(0);
        // 6. fragments + MFMA
        s16x8 af[2], bf[4];
#pragma unroll
        for (int mi = 0; mi < 2; ++mi)
            af[mi] = *(const s16x8*)(aF + mi * 16 * 40);
#pragma unroll
        for (int ni = 0; ni < 4; ++ni)
            bf[ni] = *(const s16x8*)(bF + ni * 16 * 40);
        __builtin_amdgcn_s_setprio(1);
#pragma unroll
        for (int mi = 0; mi < 2; ++mi)
#pragma unroll
            for (int ni = 0; ni < 4; ++ni)
                acc[mi][ni] = __builtin_amdgcn_mfma_f32_16x16x32_bf16(
                    af[mi], bf[ni], acc[mi][ni], 0, 0, 0);
        __builtin_amdgcn_s_setprio(0);
    }

    // Epilogue: C/D layout col = lane&15, row = (lane>>4)*4 + reg
    const int bb = m0 >> 11;            // 64 | 2048 -> constant per block
    const int coln = wn + fr;
    float gbv[4], c0v[4];
#pragma unroll
    for (int ni = 0; ni < 4; ++ni) {
        gbv[ni] = gb[bb * H_SZ + coln + ni * 16];
        c0v[ni] = c0[bb * H_SZ + coln + ni * 16];
    }
#pragma unroll
    for (int mi = 0; mi < 2; ++mi) {
#pragma unroll
        for (int r = 0; r < 4; ++r) {
            const int Mg = m0 + wm + mi * 16 + fq * 4 + r;
            const int tt = Mg & (T_SZ - 1);
            const int obase = tt * (B_SZ * H_SZ) + bb * H_SZ;
            const bool last = (tt == T_SZ - 1);
#pragma unroll
            for (int ni = 0; ni < 4; ++ni) {
                const int h = coln + ni * 16;
                float g = acc[mi][ni][r] + gbv[ni];
                float gc = fminf(15.f, fmaxf(-15.f, g));
                float e = __expf(-gc);
                float s = __builtin_amdgcn_rcpf(1.f + e);        // sigmoid(g)
                float e2 = e * e;
                float m = (1.f - e2) * __builtin_amdgcn_rcpf(1.f + e2);  // tanh(g)
                float cv = s * (c0v[ni] + m);
                float cc = fminf(15.f, fmaxf(-15.f, cv));
                float ec = __expf(-2.f * cc);
                float th = (1.f - ec) * __builtin_amdgcn_rcpf(1.f + ec); // tanh(c)
                float hv = s * th;
                out[obase + h] = hv;
                if (last) {
                    out[TBH + bb * H_SZ + h] = hv;                 // h_last
                    out[TBH + B_SZ * H_SZ + bb * H_SZ + h] = cv;   // c_last
                }
            }
        }
    }
}

extern "C" void kernel_launch(void* const* d_in, const int* in_sizes, int n_in,
                              void* d_out, int out_size, void* d_ws, size_t ws_size,
                              hipStream_t stream) {
    const float* x    = (const float*)d_in[0];
    const float* h0   = (const float*)d_in[1];
    const float* c0   = (const float*)d_in[2];
    const float* W_fi = (const float*)d_in[3];
    const float* b_fi = (const float*)d_in[4];
    const float* W_fh = (const float*)d_in[5];
    const float* b_fh = (const float*)d_in[6];
    float* out = (float*)d_out;

    unsigned short* Wb = (unsigned short*)d_ws;               // 128 KB
    float* gb = (float*)((char*)d_ws + 131072);               // 64 KB

    hipLaunchKernelGGL(prep_kernel, dim3(B_SZ), dim3(H_SZ), 0, stream,
                       h0, W_fi, b_fi, W_fh, b_fh, Wb, gb);
    hipLaunchKernelGGL(lstm_main, dim3(M_SZ / 64), dim3(512), 0, stream,
                       x, Wb, gb, c0, out);
}